// Round 6
// baseline (34.958 us; speedup 1.0000x reference)
//
#include <hip/hip_runtime.h>
#include <math.h>

// SpikingNeuron forward scan — fully-coalesced R+W, all-b128 swizzled LDS,
// register-resident scan chain, no fences (single-wave blocks, in-order DS).
//
// Forward-value semantics (stop_gradient collapses):
//   fb   = sigmoid(beta)
//   m    = init_rand * thr                      (recorded as mems[:,0] pre-step)
//   m_new = fb*m + x[:,t]        (mul then add, NO fma -- must match numpy f32)
//   surplus = m_new - thr
//   spike = (surplus >= 0) ? 1 : 0
//   m     = spike ? surplus : m_new   (surplus == m_new - 1.0f*thr, one rounding)
//
// Structure: 1 wave (64 threads) per block, 64 rows per block, 1024 blocks
// (4+ blocks/CU; occupancy structurally capped at 1 wave/SIMD -- serial scan).
// LDS tiles are [64 rows][32 cols] f32, power-of-2 row stride (128 B), with
// T2-style XOR swizzle on 16B granules: granule' = granule ^ (row & 7).
//   - every LDS access is an aligned ds_read_b128/ds_write_b128
//   - each 8-lane cluster covers all 8 bank-groups -> conflict-free
// Streams:
//   x:   8-lane groups load contiguous 128B row-chunks (coalesced float4),
//        staged swizzled into xs; scan reads its own row as 8 x b128 into
//        registers BEFORE the serial chain (no LDS latency in the chain).
//   s/m: chain produces f32x4 in regs -> 8+8 b128 writes -> writeout phase
//        reads transposed and NT-stores contiguous 128B row-chunks.
// No __syncthreads / no s_waitcnt fences: single-wave block, per-wave DS ops
// execute in order, compiler preserves aliasing-access order; vmcnt never
// drained -> NT stores and prefetch loads stay in flight across phases.

#define N_BATCH 65536
#define T_STEPS 256
#define ROWS    64          // rows per block == threads per block (1 wave)
#define CHUNK   32          // columns per chunk
#define NCHUNK  (T_STEPS / CHUNK)
#define GPR     (CHUNK / 4) // 8 granules (float4) per row-chunk

typedef float f32x4 __attribute__((ext_vector_type(4)));

// Swizzled dword offset of (row r, granule g) in a [64][32] f32 tile.
__device__ __forceinline__ int swz(int r, int g) {
    return r * CHUNK + 4 * (g ^ (r & 7));
}

__global__ __launch_bounds__(64) void snn_fwd_kernel(
    const float* __restrict__ x,
    const float* __restrict__ beta_p,
    const float* __restrict__ thr_p,
    const float* __restrict__ init_rand,
    float* __restrict__ out)
{
#pragma clang fp contract(off)
    __shared__ float xs[ROWS * CHUNK];
    __shared__ float ss[ROWS * CHUNK];
    __shared__ float ms[ROWS * CHUNK];

    const int t   = threadIdx.x;          // 0..63
    const int row = blockIdx.x * ROWS + t;

    const float thr = thr_p[0];
    // Correctly-rounded f32 sigmoid via double intermediate.
    const float fb = (float)(1.0 / (1.0 + exp(-(double)beta_p[0])));

    float m = init_rand[row] * thr;

    float* __restrict__ s_out = out;
    float* __restrict__ m_out = out + (size_t)N_BATCH * T_STEPS;

    // Cooperative geometry: 8-lane groups; lane t covers rows r0+8q,
    // 16B granule k of each row-chunk.
    const int k  = t & 7;
    const int r0 = t >> 3;

    // ---- prologue: stage chunk 0 (coalesced load -> swizzled LDS) ----
    {
        f32x4 xld[GPR];
#pragma unroll
        for (int q = 0; q < GPR; ++q) {
            const int rr = r0 + 8 * q;
            xld[q] = *reinterpret_cast<const f32x4*>(
                x + (size_t)(blockIdx.x * ROWS + rr) * T_STEPS + 4 * k);
        }
#pragma unroll
        for (int q = 0; q < GPR; ++q)
            *reinterpret_cast<f32x4*>(xs + swz(r0 + 8 * q, k)) = xld[q];
    }

#pragma unroll
    for (int cc = 0; cc < NCHUNK; ++cc) {
        // Prefetch next chunk (coalesced); latency hides under scan+writeout.
        f32x4 xnext[GPR];
        if (cc + 1 < NCHUNK) {
#pragma unroll
            for (int q = 0; q < GPR; ++q) {
                const int rr = r0 + 8 * q;
                xnext[q] = *reinterpret_cast<const f32x4*>(
                    x + (size_t)(blockIdx.x * ROWS + rr) * T_STEPS
                      + (cc + 1) * CHUNK + 4 * k);
            }
        }

        // ---- scan phase: pull own row into regs, chain in regs ----
        f32x4 xv[GPR];
#pragma unroll
        for (int i = 0; i < GPR; ++i)
            xv[i] = *reinterpret_cast<const f32x4*>(xs + swz(t, i));

#pragma unroll
        for (int i = 0; i < GPR; ++i) {
            f32x4 sv4, mv4;
#pragma unroll
            for (int j = 0; j < 4; ++j) {
                mv4[j] = m;                   // pre-step memory
                float prod = fb * m;
                float mn   = prod + xv[i][j];
                float su   = mn - thr;
                sv4[j] = (su >= 0.0f) ? 1.0f : 0.0f;
                m = (su >= 0.0f) ? su : mn;
            }
            *reinterpret_cast<f32x4*>(ss + swz(t, i)) = sv4;
            *reinterpret_cast<f32x4*>(ms + swz(t, i)) = mv4;
        }

        // ---- writeout: transposed b128 LDS reads -> coalesced NT stores ----
#pragma unroll
        for (int p = 0; p < GPR; ++p) {
            const int rr = r0 + 8 * p;
            const f32x4 sv = *reinterpret_cast<const f32x4*>(ss + swz(rr, k));
            const f32x4 mv = *reinterpret_cast<const f32x4*>(ms + swz(rr, k));
            const size_t g = (size_t)(blockIdx.x * ROWS + rr) * T_STEPS
                           + cc * CHUNK + 4 * k;
            __builtin_nontemporal_store(sv, reinterpret_cast<f32x4*>(s_out + g));
            __builtin_nontemporal_store(mv, reinterpret_cast<f32x4*>(m_out + g));
        }

        // ---- stage next x chunk into LDS (after this chunk's xs reads) ----
        if (cc + 1 < NCHUNK) {
#pragma unroll
            for (int q = 0; q < GPR; ++q)
                *reinterpret_cast<f32x4*>(xs + swz(r0 + 8 * q, k)) = xnext[q];
        }
    }
}

extern "C" void kernel_launch(void* const* d_in, const int* in_sizes, int n_in,
                              void* d_out, int out_size, void* d_ws, size_t ws_size,
                              hipStream_t stream) {
    const float* x         = (const float*)d_in[0];
    const float* beta      = (const float*)d_in[1];
    const float* threshold = (const float*)d_in[2];
    const float* init_rand = (const float*)d_in[3];
    float* out             = (float*)d_out;

    const int threads = ROWS;                 // 64 = 1 wave
    const int blocks  = N_BATCH / ROWS;       // 1024 blocks
    snn_fwd_kernel<<<blocks, threads, 0, stream>>>(x, beta, threshold, init_rand, out);
}